// Round 2
// baseline (3660.876 us; speedup 1.0000x reference)
//
#include <hip/hip_runtime.h>
#include <hip/hip_bf16.h>

#define NB 64
#define NS 512
#define NV 1000
#define NF 64
#define NH 256

typedef short bf16x8 __attribute__((ext_vector_type(8)));
typedef float f32x4 __attribute__((ext_vector_type(4)));

__device__ __forceinline__ float bf2f(unsigned int u16bits){
    union { unsigned int i; float f; } v;
    v.i = (u16bits & 0xffffu) << 16;
    return v.f;
}

// Deterministic input-dtype probe: read first 64 u16 of raw W_hh0 as bf16.
// True bf16 weights (0.05*N(0,1)) -> max ~0.2. A f32 buffer misread as bf16
// has random exponents in even slots -> huge/NaN values w.p. ~1 - 1.5e-9.
__device__ __forceinline__ bool detect_f32(const void* probe){
    const unsigned short* p = (const unsigned short*)probe;
    bool bad = false;
    float mx = 0.f;
#pragma unroll
    for (int j = 0; j < 64; ++j){
        float v = fabsf(bf2f(p[j]));
        bad = bad || !(v == v);          // NaN
        mx = fmaxf(mx, v);
    }
    return bad || (mx > 100.f);
}

// ---------------------------------------------------------------------------
// K0: canonicalize any float input (f32 or bf16, per probe) into bf16.
// ---------------------------------------------------------------------------
__global__ void k_conv(const void* __restrict__ src, __hip_bfloat16* __restrict__ dst,
                       int n, const void* __restrict__ probe){
    const bool f32in = detect_f32(probe);
    int i = blockIdx.x * blockDim.x + threadIdx.x;
    const int stride = gridDim.x * blockDim.x;
    if (f32in){
        const float* s = (const float*)src;
        for (; i < n; i += stride) dst[i] = __float2bfloat16(s[i]);
    } else {
        const unsigned short* s = (const unsigned short*)src;
        for (; i < n; i += stride) dst[i] = __float2bfloat16(bf2f(s[i]));
    }
}

// ---------------------------------------------------------------------------
// K1: pre0[v][h] = dot(features[v,:], W_ih0[h,:]) + b_ih0[h] + b_hh0[h]
// ---------------------------------------------------------------------------
__global__ void k_pre0(const __hip_bfloat16* __restrict__ feats,
                       const __hip_bfloat16* __restrict__ Wih,
                       const __hip_bfloat16* __restrict__ bih,
                       const __hip_bfloat16* __restrict__ bhh,
                       float* __restrict__ pre0){
    const int v = blockIdx.x, h = threadIdx.x;
    __shared__ __align__(16) float fsh[NF];
    if (h < NF) fsh[h] = __bfloat162float(feats[v*NF + h]);
    __syncthreads();
    const uint4* wr = reinterpret_cast<const uint4*>(Wih + h*NF); // 64 bf16 = 8 x uint4
    float acc = __bfloat162float(bih[h]) + __bfloat162float(bhh[h]);
#pragma unroll
    for (int j = 0; j < 8; ++j){
        uint4 q = wr[j];
        const float* hf = &fsh[j*8];
        acc += hf[0]*bf2f(q.x) + hf[1]*bf2f(q.x>>16)
             + hf[2]*bf2f(q.y) + hf[3]*bf2f(q.y>>16)
             + hf[4]*bf2f(q.z) + hf[5]*bf2f(q.z>>16)
             + hf[6]*bf2f(q.w) + hf[7]*bf2f(q.w>>16);
    }
    pre0[v*NH + h] = acc;
}

// ---------------------------------------------------------------------------
// K2/K4: tanh RNN recurrence, one workgroup per batch row.
// Thread t owns output index t; W_hh row t in 256 f32 VGPRs.
// LAYER 0: xp f32 gathered via batch; LAYER 1: xp bf16 dense.
// ---------------------------------------------------------------------------
template<int LAYER>
__global__ __launch_bounds__(256, 1) void k_rnn(const int* __restrict__ batch,
                                                const void* __restrict__ xp,
                                                const __hip_bfloat16* __restrict__ Whh,
                                                __hip_bfloat16* __restrict__ hout){
    const int b = blockIdx.x, t = threadIdx.x;
    float w[NH];
    {
        const uint4* wr = reinterpret_cast<const uint4*>(Whh + t*NH); // 256 bf16 = 32 x uint4
#pragma unroll
        for (int j = 0; j < 32; ++j){
            uint4 q = wr[j];
            w[j*8+0]=bf2f(q.x); w[j*8+1]=bf2f(q.x>>16);
            w[j*8+2]=bf2f(q.y); w[j*8+3]=bf2f(q.y>>16);
            w[j*8+4]=bf2f(q.z); w[j*8+5]=bf2f(q.z>>16);
            w[j*8+6]=bf2f(q.w); w[j*8+7]=bf2f(q.w>>16);
        }
    }
    __shared__ __align__(16) float hsh[NH];
    hsh[t] = 0.f;

    const float* xf = (const float*)xp;
    const unsigned short* xb = (const unsigned short*)xp;
    float xpv;
    if (LAYER == 0){ int idx = batch[b*NS + 0]; xpv = xf[idx*NH + t]; }
    else           { xpv = bf2f(xb[(size_t)(b*NS + 0)*NH + t]); }
    __syncthreads();

    for (int step = 0; step < NS; ++step){
        float xnext = 0.f;
        if (step + 1 < NS){
            if (LAYER == 0){ int idx = batch[b*NS + step + 1]; xnext = xf[idx*NH + t]; }
            else           { xnext = bf2f(xb[(size_t)(b*NS + step + 1)*NH + t]); }
        }
        float a0=0.f, a1=0.f, a2=0.f, a3=0.f;
        const float4* h4 = reinterpret_cast<const float4*>(hsh);
#pragma unroll
        for (int j = 0; j < 64; ++j){
            float4 hv = h4[j];
            a0 += hv.x * w[j*4+0];
            a1 += hv.y * w[j*4+1];
            a2 += hv.z * w[j*4+2];
            a3 += hv.w * w[j*4+3];
        }
        float hn = tanhf(xpv + ((a0+a1)+(a2+a3)));
        __syncthreads();               // all reads of hsh done
        hsh[t] = hn;
        hout[((size_t)(b*NS + step))*NH + t] = __float2bfloat16(hn);
        xpv = xnext;
        __syncthreads();               // new h visible
    }
}

// ---------------------------------------------------------------------------
// K3/K5: C[M,N] = A[M,256] @ W[N,256]^T (+bias1+bias2), MFMA 16x16x32 bf16.
// C/D layout (m89): col = lane&15, row = (lane>>4)*4 + reg.
// If probe != nullptr and input dtype was f32, store f32; else bf16.
// ---------------------------------------------------------------------------
template<int N>
__global__ void k_gemm(const __hip_bfloat16* __restrict__ A,
                       const __hip_bfloat16* __restrict__ W,
                       const __hip_bfloat16* __restrict__ bias1,
                       const __hip_bfloat16* __restrict__ bias2,
                       void* __restrict__ Cout, int ldc,
                       const void* __restrict__ probe){
    const bool f32out = probe ? detect_f32(probe) : false;
    const int m0 = blockIdx.x * 64;
    const int n0 = blockIdx.y * 64;
    const int wv = threadIdx.x >> 6;
    const int l  = threadIdx.x & 63;
    const int mrow  = m0 + wv*16 + (l & 15);
    const int kbase = (l >> 4) * 8;

    f32x4 acc[4] = {};
#pragma unroll
    for (int ks = 0; ks < 8; ++ks){
        bf16x8 af = *reinterpret_cast<const bf16x8*>(A + (size_t)mrow*NH + ks*32 + kbase);
#pragma unroll
        for (int nt = 0; nt < 4; ++nt){
            int ncol = n0 + nt*16 + (l & 15);
            int nc = (ncol < N) ? ncol : (N-1);   // clamp; garbage cols never stored
            bf16x8 bfr = *reinterpret_cast<const bf16x8*>(W + (size_t)nc*NH + ks*32 + kbase);
            acc[nt] = __builtin_amdgcn_mfma_f32_16x16x32_bf16(af, bfr, acc[nt], 0, 0, 0);
        }
    }
#pragma unroll
    for (int nt = 0; nt < 4; ++nt){
        int ncol = n0 + nt*16 + (l & 15);
        if (ncol >= N) continue;
        float bsum = __bfloat162float(bias1[ncol]) + (bias2 ? __bfloat162float(bias2[ncol]) : 0.f);
#pragma unroll
        for (int r = 0; r < 4; ++r){
            int row = m0 + wv*16 + (l>>4)*4 + r;
            float val = acc[nt][r] + bsum;
            if (f32out) ((float*)Cout)[(size_t)row*ldc + ncol] = val;
            else        ((__hip_bfloat16*)Cout)[(size_t)row*ldc + ncol] = __float2bfloat16(val);
        }
    }
}

// ---------------------------------------------------------------------------
extern "C" void kernel_launch(void* const* d_in, const int* in_sizes, int n_in,
                              void* d_out, int out_size, void* d_ws, size_t ws_size,
                              hipStream_t stream){
    const int* batch = (const int*)d_in[0];
    const void* probe = d_in[3];  // raw W_hh0, used for dtype detection

    char* ws = (char*)d_ws;
    size_t off = 0;
    auto give = [&](size_t bytes)->char*{
        char* p = ws + off; off = (off + bytes + 511) & ~(size_t)511; return p;
    };
    __hip_bfloat16* cFeats = (__hip_bfloat16*)give(2*NV*NF);
    __hip_bfloat16* cWih0  = (__hip_bfloat16*)give(2*NH*NF);
    __hip_bfloat16* cWhh0  = (__hip_bfloat16*)give(2*NH*NH);
    __hip_bfloat16* cBih0  = (__hip_bfloat16*)give(2*NH);
    __hip_bfloat16* cBhh0  = (__hip_bfloat16*)give(2*NH);
    __hip_bfloat16* cWih1  = (__hip_bfloat16*)give(2*NH*NH);
    __hip_bfloat16* cWhh1  = (__hip_bfloat16*)give(2*NH*NH);
    __hip_bfloat16* cBih1  = (__hip_bfloat16*)give(2*NH);
    __hip_bfloat16* cBhh1  = (__hip_bfloat16*)give(2*NH);
    __hip_bfloat16* cWout  = (__hip_bfloat16*)give(2*NV*NH);
    __hip_bfloat16* cBout  = (__hip_bfloat16*)give(2*NV);
    float*          pre0   = (float*)give(4*NV*NH);
    __hip_bfloat16* hbuf   = (__hip_bfloat16*)give(2*(size_t)NB*NS*NH);
    __hip_bfloat16* xp1    = (__hip_bfloat16*)give(2*(size_t)NB*NS*NH);
    // total ~35.5 MiB

    struct { const void* src; __hip_bfloat16* dst; int n; } cv[11] = {
        { d_in[1],  cFeats, NV*NF }, { d_in[2],  cWih0, NH*NF },
        { d_in[3],  cWhh0,  NH*NH }, { d_in[4],  cBih0, NH },
        { d_in[5],  cBhh0,  NH },    { d_in[6],  cWih1, NH*NH },
        { d_in[7],  cWhh1,  NH*NH }, { d_in[8],  cBih1, NH },
        { d_in[9],  cBhh1,  NH },    { d_in[10], cWout, NV*NH },
        { d_in[11], cBout,  NV },
    };
    for (int i = 0; i < 11; ++i){
        int grid = (cv[i].n + 255) / 256; if (grid > 512) grid = 512;
        k_conv<<<dim3(grid), dim3(256), 0, stream>>>(cv[i].src, cv[i].dst, cv[i].n, probe);
    }

    k_pre0<<<dim3(NV), dim3(256), 0, stream>>>(cFeats, cWih0, cBih0, cBhh0, pre0);
    k_rnn<0><<<dim3(NB), dim3(256), 0, stream>>>(batch, pre0, cWhh0, hbuf);
    k_gemm<NH><<<dim3((NB*NS)/64, NH/64), dim3(256), 0, stream>>>(
        hbuf, cWih1, cBih1, cBhh1, xp1, NH, nullptr);
    k_rnn<1><<<dim3(NB), dim3(256), 0, stream>>>(batch, xp1, cWhh1, hbuf);
    k_gemm<NV><<<dim3((NB*NS)/64, 16), dim3(256), 0, stream>>>(
        hbuf, cWout, cBout, nullptr, d_out, NV, probe);
}

// Round 4
// 1056.233 us; speedup vs baseline: 3.4660x; 3.4660x over previous
//
#include <hip/hip_runtime.h>
#include <hip/hip_bf16.h>

#define NB 64
#define NS 512
#define NV 1000
#define NF 64
#define NH 256

typedef short bf16x8 __attribute__((ext_vector_type(8)));
typedef float f32x4 __attribute__((ext_vector_type(4)));

__device__ __forceinline__ float bf2f(unsigned int u16bits){
    union { unsigned int i; float f; } v;
    v.i = (u16bits & 0xffffu) << 16;
    return v.f;
}

__device__ __forceinline__ unsigned pack2bf(float a, float b){
    union { float f; unsigned u; } x, y; x.f = a; y.f = b;
    unsigned lo = (x.u + 0x7FFFu + ((x.u >> 16) & 1u)) >> 16;
    unsigned hi = (y.u + 0x7FFFu + ((y.u >> 16) & 1u)) >> 16;
    return (lo & 0xFFFFu) | (hi << 16);
}

__device__ __forceinline__ float tanh_fast(float x){
    // tanh(x) = 1 - 2/(exp2(2*log2e*x)+1); large-|x| limits give +-1 correctly
    float e = __builtin_amdgcn_exp2f(x * 2.8853900817779268f);
    return 1.f - 2.f * __builtin_amdgcn_rcpf(e + 1.f);
}

// Deterministic input-dtype probe (see round 1->2): bf16-read of f32 data is huge/NaN.
__device__ __forceinline__ bool detect_f32(const void* probe){
    const unsigned short* p = (const unsigned short*)probe;
    bool bad = false; float mx = 0.f;
#pragma unroll
    for (int j = 0; j < 64; ++j){
        float v = fabsf(bf2f(p[j]));
        bad = bad || !(v == v);
        mx = fmaxf(mx, v);
    }
    return bad || (mx > 100.f);
}

// ---------------------------------------------------------------------------
// K0: canonicalize all 11 float inputs into bf16 — ONE launch.
// ---------------------------------------------------------------------------
struct ConvArgs { const void* src[11]; __hip_bfloat16* dst[11]; int n[11]; };

__global__ void k_conv_all(ConvArgs a, const void* __restrict__ probe){
    const int seg = blockIdx.y;
    const int n = a.n[seg];
    int i = blockIdx.x * 256 + threadIdx.x;
    if (i >= n) return;
    const bool f32in = detect_f32(probe);
    const int stride = gridDim.x * 256;
    __hip_bfloat16* dst = a.dst[seg];
    if (f32in){
        const float* s = (const float*)a.src[seg];
        for (; i < n; i += stride) dst[i] = __float2bfloat16(s[i]);
    } else {
        const unsigned short* s = (const unsigned short*)a.src[seg];
        for (; i < n; i += stride) dst[i] = __float2bfloat16(bf2f(s[i]));
    }
}

// ---------------------------------------------------------------------------
// K1: pre0[v][h] = dot(features[v,:], W_ih0[h,:]) + b_ih0[h] + b_hh0[h]  (f32)
// ---------------------------------------------------------------------------
__global__ void k_pre0(const __hip_bfloat16* __restrict__ feats,
                       const __hip_bfloat16* __restrict__ Wih,
                       const __hip_bfloat16* __restrict__ bih,
                       const __hip_bfloat16* __restrict__ bhh,
                       float* __restrict__ pre0){
    const int v = blockIdx.x, h = threadIdx.x;
    __shared__ __align__(16) float fsh[NF];
    if (h < NF) fsh[h] = __bfloat162float(feats[v*NF + h]);
    __syncthreads();
    const uint4* wr = reinterpret_cast<const uint4*>(Wih + h*NF);
    float acc = __bfloat162float(bih[h]) + __bfloat162float(bhh[h]);
#pragma unroll
    for (int j = 0; j < 8; ++j){
        uint4 q = wr[j];
        const float* hf = &fsh[j*8];
        acc += hf[0]*bf2f(q.x) + hf[1]*bf2f(q.x>>16)
             + hf[2]*bf2f(q.y) + hf[3]*bf2f(q.y>>16)
             + hf[4]*bf2f(q.z) + hf[5]*bf2f(q.z>>16)
             + hf[6]*bf2f(q.w) + hf[7]*bf2f(q.w>>16);
    }
    pre0[v*NH + h] = acc;
}

// ---------------------------------------------------------------------------
// K2/K4: MFMA RNN recurrence. Grid = 4 WGs x 512 threads (8 waves), 16 batch
// rows per WG. Per step: D[c, brow] = Whh @ H^T via mfma_f32_16x16x32_bf16:
//   A = Whh frags (registers, 64 VGPR/thread, loaded once)
//   B = H frags from LDS (XOR-swizzled [16][256] bf16, double-buffered)
//   D: thread owns 4 k-consecutive cols per tile -> pack -> ds_write_b64.
// LAYER 0: xp = pre0[batch[b0+lr][s]][c] (f32, L2-resident), prefetched.
// LAYER 1: xp = xp1[b0+lr][s][c] (bf16 stream), prefetched.
// ---------------------------------------------------------------------------
template<int LAYER>
__global__ __launch_bounds__(512, 1) void k_rnn(const int* __restrict__ batch,
                                                const void* __restrict__ xpv,
                                                const __hip_bfloat16* __restrict__ Whh,
                                                __hip_bfloat16* __restrict__ hout){
    const int w  = threadIdx.x >> 6;
    const int l  = threadIdx.x & 63;
    const int b0 = blockIdx.x * 16;
    const int lr = l & 15;          // lane row: batch-row (B/D) and Whh out-col (A)
    const int kq = l >> 4;          // 0..3 k-quarter
    const int c0 = w * 32;          // wave's output-col base

    // Whh A-frags: lane holds Whh[c0+nt*16+lr][ks*32+kq*8 .. +8]
    bf16x8 wf[2][8];
#pragma unroll
    for (int nt = 0; nt < 2; ++nt)
#pragma unroll
        for (int ks = 0; ks < 8; ++ks)
            wf[nt][ks] = *reinterpret_cast<const bf16x8*>(
                Whh + (size_t)(c0 + nt*16 + lr)*NH + ks*32 + kq*8);

    __shared__ __align__(16) unsigned short hsh[2][4096];  // 2 x [16][256] bf16, swizzled
    *reinterpret_cast<uint4*>(&hsh[0][threadIdx.x*8]) = uint4{0,0,0,0};

    const float*          xf = (const float*)xpv;
    const unsigned short* xb = (const unsigned short*)xpv;

    int roff[8];
#pragma unroll
    for (int ks = 0; ks < 8; ++ks)
        roff[ks] = lr*512 + ((ks*64 + kq*16) ^ ((lr & 7) << 4));
    const int woff0 = lr*512 + (((c0 + 0*16 + kq*4)*2) ^ ((lr & 7) << 4));
    const int woff1 = lr*512 + (((c0 + 1*16 + kq*4)*2) ^ ((lr & 7) << 4));

    // prefetch state for step 0
    float4 xq0, xq1; ushort4 bq0, bq1; int idx1 = 0;
    if (LAYER == 0){
        int idx0 = batch[(b0 + lr)*NS + 0];
        xq0 = *reinterpret_cast<const float4*>(xf + idx0*NH + c0 + 0*16 + kq*4);
        xq1 = *reinterpret_cast<const float4*>(xf + idx0*NH + c0 + 1*16 + kq*4);
        idx1 = batch[(b0 + lr)*NS + 1];
    } else {
        const unsigned short* base = xb + ((size_t)(b0+lr)*NS + 0)*NH;
        bq0 = *reinterpret_cast<const ushort4*>(base + c0 + 0*16 + kq*4);
        bq1 = *reinterpret_cast<const ushort4*>(base + c0 + 1*16 + kq*4);
    }
    __syncthreads();

    int cur = 0;
    for (int s = 0; s < NS; ++s){
        // issue next step's xp prefetch
        float4 nxq0 = {}, nxq1 = {}; ushort4 nbq0 = {}, nbq1 = {}; int idx2 = 0;
        if (s + 1 < NS){
            if (LAYER == 0){
                nxq0 = *reinterpret_cast<const float4*>(xf + idx1*NH + c0 + 0*16 + kq*4);
                nxq1 = *reinterpret_cast<const float4*>(xf + idx1*NH + c0 + 1*16 + kq*4);
                if (s + 2 < NS) idx2 = batch[(b0 + lr)*NS + s + 2];
            } else {
                const unsigned short* base = xb + ((size_t)(b0+lr)*NS + (s+1))*NH;
                nbq0 = *reinterpret_cast<const ushort4*>(base + c0 + 0*16 + kq*4);
                nbq1 = *reinterpret_cast<const ushort4*>(base + c0 + 1*16 + kq*4);
            }
        }
        // H B-frags from LDS
        const char* rbuf = (const char*)hsh[cur];
        bf16x8 hf[8];
#pragma unroll
        for (int ks = 0; ks < 8; ++ks)
            hf[ks] = *reinterpret_cast<const bf16x8*>(rbuf + roff[ks]);

        f32x4 acc0 = {}, acc1 = {};
#pragma unroll
        for (int ks = 0; ks < 8; ++ks){
            acc0 = __builtin_amdgcn_mfma_f32_16x16x32_bf16(wf[0][ks], hf[ks], acc0, 0,0,0);
            acc1 = __builtin_amdgcn_mfma_f32_16x16x32_bf16(wf[1][ks], hf[ks], acc1, 0,0,0);
        }
        float t0[4], t1[4];
#pragma unroll
        for (int r = 0; r < 4; ++r){
            float x0, x1;
            if (LAYER == 0){ x0 = ((const float*)&xq0)[r];        x1 = ((const float*)&xq1)[r]; }
            else           { x0 = bf2f(((const ushort*)&bq0)[r]); x1 = bf2f(((const ushort*)&bq1)[r]); }
            t0[r] = tanh_fast(acc0[r] + x0);
            t1[r] = tanh_fast(acc1[r] + x1);
        }
        uint2 p0 = { pack2bf(t0[0], t0[1]), pack2bf(t0[2], t0[3]) };
        uint2 p1 = { pack2bf(t1[0], t1[1]), pack2bf(t1[2], t1[3]) };

        char* wbuf = (char*)hsh[cur ^ 1];
        *reinterpret_cast<uint2*>(wbuf + woff0) = p0;
        *reinterpret_cast<uint2*>(wbuf + woff1) = p1;
        __hip_bfloat16* ho = hout + ((size_t)(b0+lr)*NS + s)*NH;
        *reinterpret_cast<uint2*>(ho + c0 + 0*16 + kq*4) = p0;
        *reinterpret_cast<uint2*>(ho + c0 + 1*16 + kq*4) = p1;

        if (LAYER == 0){ xq0 = nxq0; xq1 = nxq1; idx1 = idx2; }
        else           { bq0 = nbq0; bq1 = nbq1; }
        __syncthreads();
        cur ^= 1;
    }
}

// ---------------------------------------------------------------------------
// K3/K5: C[M,N] = A[M,256] @ W[N,256]^T (+bias1+bias2), MFMA 16x16x32 bf16.
// ---------------------------------------------------------------------------
template<int N>
__global__ void k_gemm(const __hip_bfloat16* __restrict__ A,
                       const __hip_bfloat16* __restrict__ W,
                       const __hip_bfloat16* __restrict__ bias1,
                       const __hip_bfloat16* __restrict__ bias2,
                       void* __restrict__ Cout, int ldc,
                       const void* __restrict__ probe){
    const bool f32out = probe ? detect_f32(probe) : false;
    const int m0 = blockIdx.x * 64;
    const int n0 = blockIdx.y * 64;
    const int wv = threadIdx.x >> 6;
    const int l  = threadIdx.x & 63;
    const int mrow  = m0 + wv*16 + (l & 15);
    const int kbase = (l >> 4) * 8;

    f32x4 acc[4] = {};
#pragma unroll
    for (int ks = 0; ks < 8; ++ks){
        bf16x8 af = *reinterpret_cast<const bf16x8*>(A + (size_t)mrow*NH + ks*32 + kbase);
#pragma unroll
        for (int nt = 0; nt < 4; ++nt){
            int ncol = n0 + nt*16 + (l & 15);
            int nc = (ncol < N) ? ncol : (N-1);
            bf16x8 bfr = *reinterpret_cast<const bf16x8*>(W + (size_t)nc*NH + ks*32 + kbase);
            acc[nt] = __builtin_amdgcn_mfma_f32_16x16x32_bf16(af, bfr, acc[nt], 0, 0, 0);
        }
    }
#pragma unroll
    for (int nt = 0; nt < 4; ++nt){
        int ncol = n0 + nt*16 + (l & 15);
        if (ncol >= N) continue;
        float bsum = __bfloat162float(bias1[ncol]) + (bias2 ? __bfloat162float(bias2[ncol]) : 0.f);
#pragma unroll
        for (int r = 0; r < 4; ++r){
            int row = m0 + wv*16 + (l>>4)*4 + r;
            float val = acc[nt][r] + bsum;
            if (f32out) ((float*)Cout)[(size_t)row*ldc + ncol] = val;
            else        ((__hip_bfloat16*)Cout)[(size_t)row*ldc + ncol] = __float2bfloat16(val);
        }
    }
}

// ---------------------------------------------------------------------------
extern "C" void kernel_launch(void* const* d_in, const int* in_sizes, int n_in,
                              void* d_out, int out_size, void* d_ws, size_t ws_size,
                              hipStream_t stream){
    const int* batch = (const int*)d_in[0];
    const void* probe = d_in[3];  // raw W_hh0 for dtype detection

    char* ws = (char*)d_ws;
    size_t off = 0;
    auto give = [&](size_t bytes)->char*{
        char* p = ws + off; off = (off + bytes + 511) & ~(size_t)511; return p;
    };
    __hip_bfloat16* cFeats = (__hip_bfloat16*)give(2*NV*NF);
    __hip_bfloat16* cWih0  = (__hip_bfloat16*)give(2*NH*NF);
    __hip_bfloat16* cWhh0  = (__hip_bfloat16*)give(2*NH*NH);
    __hip_bfloat16* cBih0  = (__hip_bfloat16*)give(2*NH);
    __hip_bfloat16* cBhh0  = (__hip_bfloat16*)give(2*NH);
    __hip_bfloat16* cWih1  = (__hip_bfloat16*)give(2*NH*NH);
    __hip_bfloat16* cWhh1  = (__hip_bfloat16*)give(2*NH*NH);
    __hip_bfloat16* cBih1  = (__hip_bfloat16*)give(2*NH);
    __hip_bfloat16* cBhh1  = (__hip_bfloat16*)give(2*NH);
    __hip_bfloat16* cWout  = (__hip_bfloat16*)give(2*NV*NH);
    __hip_bfloat16* cBout  = (__hip_bfloat16*)give(2*NV);
    float*          pre0   = (float*)give(4*NV*NH);
    __hip_bfloat16* hbuf   = (__hip_bfloat16*)give(2*(size_t)NB*NS*NH);
    __hip_bfloat16* xp1    = (__hip_bfloat16*)give(2*(size_t)NB*NS*NH);

    ConvArgs ca;
    const void* srcs[11] = { d_in[1], d_in[2], d_in[3], d_in[4], d_in[5], d_in[6],
                             d_in[7], d_in[8], d_in[9], d_in[10], d_in[11] };
    __hip_bfloat16* dsts[11] = { cFeats, cWih0, cWhh0, cBih0, cBhh0, cWih1,
                                 cWhh1, cBih1, cBhh1, cWout, cBout };
    int ns[11] = { NV*NF, NH*NF, NH*NH, NH, NH, NH*NH, NH*NH, NH, NH, NV*NH, NV };
    for (int i = 0; i < 11; ++i){ ca.src[i] = srcs[i]; ca.dst[i] = dsts[i]; ca.n[i] = ns[i]; }
    k_conv_all<<<dim3(500, 11), dim3(256), 0, stream>>>(ca, probe);

    k_pre0<<<dim3(NV), dim3(256), 0, stream>>>(cFeats, cWih0, cBih0, cBhh0, pre0);
    k_rnn<0><<<dim3(NB/16), dim3(512), 0, stream>>>(batch, pre0, cWhh0, hbuf);
    k_gemm<NH><<<dim3((NB*NS)/64, NH/64), dim3(256), 0, stream>>>(
        hbuf, cWih1, cBih1, cBhh1, xp1, NH, nullptr);
    k_rnn<1><<<dim3(NB/16), dim3(512), 0, stream>>>(batch, xp1, cWhh1, hbuf);
    k_gemm<NV><<<dim3((NB*NS)/64, 16), dim3(256), 0, stream>>>(
        hbuf, cWout, cBout, nullptr, d_out, NV, probe);
}